// Round 22
// baseline (264.855 us; speedup 1.0000x reference)
//
#include <hip/hip_runtime.h>
#include <hip/hip_bf16.h>

#define LRELU(x) ((x) >= 0.f ? (x) : 0.01f * (x))

typedef __attribute__((ext_vector_type(8))) short short8v;
typedef __attribute__((ext_vector_type(4))) float f32x4;

__device__ inline unsigned fenc(float x) {
    unsigned u = __float_as_uint(x);
    return (u & 0x80000000u) ? ~u : (u | 0x80000000u);
}
__device__ inline float fdec(unsigned e) {
    return __uint_as_float((e & 0x80000000u) ? (e ^ 0x80000000u) : ~e);
}

__device__ inline float wred(float v) {
#pragma unroll
    for (int o = 32; o > 0; o >>= 1) v += __shfl_xor(v, o, 64);
    return v;
}
__device__ inline float wredmax(float v) {
#pragma unroll
    for (int o = 32; o > 0; o >>= 1) v = fmaxf(v, __shfl_xor(v, o, 64));
    return v;
}

__device__ inline unsigned short f2bu(float x) {
    __hip_bfloat16 b = __float2bfloat16(x);
    return *reinterpret_cast<unsigned short*>(&b);
}
__device__ inline float bu2f(unsigned short u) {
    return __uint_as_float((unsigned)u << 16);
}

__device__ inline f32x4 mfma16(short8v a, short8v b, f32x4 c) {
    return __builtin_amdgcn_mfma_f32_16x16x32_bf16(a, b, c, 0, 0, 0);
}

// async global->LDS, 16B per lane, dest = (wave-uniform base) + lane*16
__device__ inline void gload16(const void* g, void* l) {
    __builtin_amdgcn_global_load_lds(
        (const __attribute__((address_space(1))) void*)g,
        (__attribute__((address_space(3))) void*)l, 16, 0, 0);
}

// ---- fused prelude: convW + rel-dot + class histogram in ONE launch ----
__global__ __launch_bounds__(256) void k_prelude(
    const float* __restrict__ wh, const float* __restrict__ wt,
    const float* __restrict__ hww, unsigned short* __restrict__ wtb_hi,
    unsigned short* __restrict__ hwt_hi,
    const float* __restrict__ remb, const float* __restrict__ ar2,
    float* __restrict__ er2, int NR,
    const int* __restrict__ cidx, int* __restrict__ cnt, int E,
    int nbConv, int nbRel) {
    int bx = blockIdx.x, tid = threadIdx.x;
    if (bx < nbConv) {
        int id = bx * 256 + tid;
        if (id < 256 * 256) {
            int n = id >> 8, k = id & 255;
            float v = (n < 128) ? wh[(size_t)k * 128 + n]
                                : wt[(size_t)k * 128 + (n - 128)];
            wtb_hi[(size_t)n * 256 + k] = f2bu(v);
        } else {
            int id2 = id - 256 * 256;
            if (id2 < 128 * 128) {
                int n = id2 >> 7, k = id2 & 127;
                hwt_hi[(size_t)n * 128 + k] = f2bu(hww[(size_t)k * 128 + n]);
            }
        }
    } else if (bx < nbConv + nbRel) {
        int lane = tid & 63;
        int r = (bx - nbConv) * 4 + (tid >> 6);
        if (r >= NR) return;
        float v0 = remb[(size_t)r * 128 + lane];
        float v1 = remb[(size_t)r * 128 + 64 + lane];
        float p2 = wred(v0 * ar2[lane] + v1 * ar2[64 + lane]);
        if (lane == 0) er2[r] = p2;
    } else {
        int i = (bx - nbConv - nbRel) * 256 + tid;
        if (i >= E) return;
        atomicAdd(&cnt[cidx[i]], 1);
    }
}

// ---- projection GEMM: 8-wave block, both col-halves, A reg-staged bf16 ----
// Block 128 rows x 256 cols (wh||wt), 8 waves = rowgroup (w&3) x col-half
// (w>>2); acc[2][8]/wave. A: each thread loads 32B f32 from global (early),
// cvt->bf16, ds_write_b128 after MFMA phase (write-late). B via
// global_load_lds. LDS 48KB -> 3 blocks/CU. One barrier/step.
__global__ __launch_bounds__(512) void k_mm_proj(
    const float* __restrict__ Af32, const unsigned short* __restrict__ Bh,
    unsigned short* __restrict__ oh0, unsigned short* __restrict__ oh1, int M,
    const float* __restrict__ ah2, const float* __restrict__ ah3,
    const float* __restrict__ ah4, const float* __restrict__ at2,
    const float* __restrict__ at3,
    float* __restrict__ hb, float* __restrict__ eh4o,
    float2* __restrict__ pta, const int* __restrict__ tidxg) {
    constexpr int KD = 256;
    constexpr int NSTEP = KD / 32;
    __shared__ unsigned short As_h[2][128 * 32];
    __shared__ unsigned short Bs_h[2][256 * 32];

    int row0 = blockIdx.x * 128;
    if (row0 + 128 > M) row0 = M - 128;
    int tid = threadIdx.x, w = tid >> 6, l = tid & 63;
    int rg = w & 3, ch = w >> 2;
    int lr = l & 15, hi4 = l >> 4;
    int srow = l >> 2, sslot = l & 3;
    // A staging: thread -> (row, 16B granule); source granule swizzled to
    // match the fragment-read XOR (involutive, conflict-free both sides)
    int arow = tid >> 2, asg = tid & 3;
    int asgl = asg ^ ((arow >> 1) & 3);
    float4 rA0, rA1;

    f32x4 acc[2][8];
#pragma unroll
    for (int i = 0; i < 2; i++)
#pragma unroll
        for (int j = 0; j < 8; j++) acc[i][j] = (f32x4){0.f, 0.f, 0.f, 0.f};

    auto loadA = [&](int s) {
        const float* p = Af32 + (size_t)(row0 + arow) * KD + s * 32 + asgl * 8;
        rA0 = *(const float4*)p;
        rA1 = *(const float4*)(p + 4);
    };
    auto writeA = [&](int b) {
        short8v v;
        v[0] = (short)f2bu(rA0.x); v[1] = (short)f2bu(rA0.y);
        v[2] = (short)f2bu(rA0.z); v[3] = (short)f2bu(rA0.w);
        v[4] = (short)f2bu(rA1.x); v[5] = (short)f2bu(rA1.y);
        v[6] = (short)f2bu(rA1.z); v[7] = (short)f2bu(rA1.w);
        *(short8v*)&As_h[b][arow * 32 + asg * 8] = v;
    };
    auto stageB = [&](int s, int b) {
        int k0 = s * 32;
#pragma unroll
        for (int i = 0; i < 2; i++) {            // 16 units of 1KB, 2/wave
            int ub = w * 2 + i;
            int n = ub * 16 + srow;              // n in [0,256): wh||wt cols
            int klog = (sslot ^ ((n >> 1) & 3)) * 8;
            gload16(Bh + (size_t)n * KD + k0 + klog,
                    (char*)&Bs_h[b][0] + ub * 1024);
        }
    };

    loadA(0);
    stageB(0, 0);
    writeA(0);
    __syncthreads();                              // buf0 ready
    for (int s = 0; s < NSTEP; s++) {
        int b = s & 1;
        if (s + 1 < NSTEP) {
            loadA(s + 1);                         // issue early (T14)
            stageB(s + 1, b ^ 1);
        }

        short8v am_h[2];
#pragma unroll
        for (int mr = 0; mr < 2; mr++) {
            int r = rg * 32 + mr * 16 + lr;
            int ko = (hi4 ^ ((r >> 1) & 3)) * 8;
            am_h[mr] = *(const short8v*)&As_h[b][r * 32 + ko];
        }
#pragma unroll
        for (int ncc = 0; ncc < 8; ncc += 4) {   // split B loads: cap VGPR
            short8v bn_h[4];
#pragma unroll
            for (int j = 0; j < 4; j++) {
                int n = ch * 128 + (ncc + j) * 16 + lr;
                int ko = (hi4 ^ ((n >> 1) & 3)) * 8;
                bn_h[j] = *(const short8v*)&Bs_h[b][n * 32 + ko];
            }
#pragma unroll
            for (int mr = 0; mr < 2; mr++)
#pragma unroll
                for (int j = 0; j < 4; j++)
                    acc[mr][ncc + j] = mfma16(am_h[mr], bn_h[j], acc[mr][ncc + j]);
        }
        if (s + 1 < NSTEP) writeA(b ^ 1);        // write late, under MFMA shadow
        __syncthreads();  // drains loads/writes + protects buffer swap
    }

    unsigned short* OH = ch ? oh1 : oh0;
    const float* v1 = ch ? at2 : ah2;
    const float* v2 = ch ? at3 : ah3;
#pragma unroll
    for (int mr = 0; mr < 2; mr++)
#pragma unroll
        for (int rr = 0; rr < 4; rr++) {
            int row = row0 + rg * 32 + mr * 16 + hi4 * 4 + rr;
            float d0 = 0.f, d1 = 0.f, d2 = 0.f;
#pragma unroll
            for (int nc = 0; nc < 8; nc++) {
                float v = fmaxf(acc[mr][nc][rr], 0.f);
                int col = nc * 16 + lr;
                d0 = fmaf(v, v1[col], d0);
                d1 = fmaf(v, v2[col], d1);
                d2 = ch ? fmaf(v, v, d2) : fmaf(v, ah4[col], d2);
            }
#pragma unroll
            for (int o = 1; o <= 8; o <<= 1) {   // reduce within 16-lane group
                d0 += __shfl_xor(d0, o, 64);
                d1 += __shfl_xor(d1, o, 64);
                d2 += __shfl_xor(d2, o, 64);
            }
            float inv = 1.f;
            if (ch) inv = 1.f / fmaxf(sqrtf(d2), 1e-12f);
#pragma unroll
            for (int nc = 0; nc < 8; nc++) {
                float v = fmaxf(acc[mr][nc][rr], 0.f);
                OH[(size_t)row * 128 + nc * 16 + lr] = f2bu(ch ? v * inv : v);
            }
            if (lr == 0) {
                if (ch == 0) {
                    hb[row] = d0 + 0.25f * d1;
                    eh4o[row] = d2;
                } else {
                    float tav = (d0 + 0.25f * d1) * inv;
                    pta[row] = make_float2(tav, __int_as_float(tidxg[row]));
                }
            }
        }
}

// ---- highway GEMM: 8-wave 256-row block (KD=128, A bf16) ----
__global__ __launch_bounds__(512) void k_mm_hw(
    const unsigned short* __restrict__ Ah, const unsigned short* __restrict__ Bh,
    float* __restrict__ o0, const float* __restrict__ bias,
    const float* __restrict__ xeh, const unsigned* __restrict__ m3f, int M) {
    constexpr int KD = 128;
    constexpr int NSTEP = KD / 32;
    __shared__ unsigned short As_h[2][256 * 32];
    __shared__ unsigned short Bs_h[2][128 * 32];

    int row0 = blockIdx.x * 256;
    if (row0 + 256 > M) row0 = M - 256;
    int tid = threadIdx.x, w = tid >> 6, l = tid & 63;
    int lr = l & 15, hi4 = l >> 4;
    int srow = l >> 2, sslot = l & 3;

    f32x4 acc[2][8];
#pragma unroll
    for (int i = 0; i < 2; i++)
#pragma unroll
        for (int j = 0; j < 8; j++) acc[i][j] = (f32x4){0.f, 0.f, 0.f, 0.f};

    auto stage = [&](int s, int b) {
        int k0 = s * 32;
#pragma unroll
        for (int i = 0; i < 3; i++) {
            int u = w * 3 + i;
            if (u < 16) {
                int row = u * 16 + srow;
                int klog = (sslot ^ ((row >> 1) & 3)) * 8;
                gload16(Ah + (size_t)(row0 + row) * KD + k0 + klog,
                        (char*)&As_h[b][0] + u * 1024);
            } else {
                int ub = u - 16;
                int row = ub * 16 + srow;
                int klog = (sslot ^ ((row >> 1) & 3)) * 8;
                gload16(Bh + (size_t)row * KD + k0 + klog,
                        (char*)&Bs_h[b][0] + ub * 1024);
            }
        }
    };

    stage(0, 0);
    __syncthreads();
    for (int s = 0; s < NSTEP; s++) {
        int b = s & 1;
        if (s + 1 < NSTEP) stage(s + 1, b ^ 1);
        short8v am_h[2];
#pragma unroll
        for (int mr = 0; mr < 2; mr++) {
            int r = w * 32 + mr * 16 + lr;
            int ko = (hi4 ^ ((r >> 1) & 3)) * 8;
            am_h[mr] = *(const short8v*)&As_h[b][r * 32 + ko];
        }
#pragma unroll
        for (int ncc = 0; ncc < 8; ncc += 4) {
            short8v bn_h[4];
#pragma unroll
            for (int j = 0; j < 4; j++) {
                int n = (ncc + j) * 16 + lr;
                int ko = (hi4 ^ ((n >> 1) & 3)) * 8;
                bn_h[j] = *(const short8v*)&Bs_h[b][n * 32 + ko];
            }
#pragma unroll
            for (int mr = 0; mr < 2; mr++)
#pragma unroll
                for (int j = 0; j < 4; j++)
                    acc[mr][ncc + j] = mfma16(am_h[mr], bn_h[j], acc[mr][ncc + j]);
        }
        __syncthreads();
    }

#pragma unroll
    for (int mr = 0; mr < 2; mr++)
#pragma unroll
        for (int rr = 0; rr < 4; rr++) {
            int row = row0 + w * 32 + mr * 16 + hi4 * 4 + rr;
            bool touched = (m3f[row] != 0u);
#pragma unroll
            for (int nc = 0; nc < 8; nc++) {
                int col = nc * 16 + lr;
                float a = acc[mr][nc][rr] + bias[col];
                float g = 1.f / (1.f + expf(-a));
                size_t o = (size_t)row * 128 + col;
                float af = bu2f(Ah[o]);
                float xv = 0.f;
                if (touched) xv = xeh[o];
                o0[o] = g * xv + (1.f - g) * af;
            }
        }
}

__global__ __launch_bounds__(1024) void k_scan(const int* __restrict__ cnt,
                                               int* __restrict__ off,
                                               int* __restrict__ cur, int NC) {
    __shared__ int wt[16];
    __shared__ int sbase;
    int tid = threadIdx.x, w = tid >> 6, lane = tid & 63;
    if (tid == 0) sbase = 0;
    __syncthreads();
    for (int c0 = 0; c0 < NC; c0 += 1024) {
        int c = c0 + tid;
        int v = (c < NC) ? cnt[c] : 0;
        int x = v;
#pragma unroll
        for (int o = 1; o < 64; o <<= 1) {
            int t = __shfl_up(x, o, 64);
            if (lane >= o) x += t;
        }
        if (lane == 63) wt[w] = x;
        __syncthreads();
        int pre = 0, tot = 0;
#pragma unroll
        for (int i = 0; i < 16; i++) {
            int t = wt[i];
            tot += t;
            if (i < w) pre += t;
        }
        int excl = sbase + pre + x - v;
        if (c < NC) { off[c] = excl; cur[c] = excl; }
        __syncthreads();
        if (tid == 0) sbase += tot;
        __syncthreads();
    }
}

// ---- fused level-2 logit + scatter (packed 8B gather + packed 8B write) ----
__global__ __launch_bounds__(256) void k_edgescatter(
    const int* __restrict__ cidx, int* __restrict__ cur,
    const int* __restrict__ hidx, const int* __restrict__ tidx,
    const int* __restrict__ rel, const float2* __restrict__ pta,
    const float* __restrict__ hb, const float* __restrict__ er2,
    float2* __restrict__ e2gs, int E) {
    int i = blockIdx.x * 256 + threadIdx.x;
    if (i >= E) return;
    int pos = atomicAdd(&cur[cidx[i]], 1);
    float2 p = pta[tidx[i]];
    float z2 = p.x + hb[hidx[i]] + 0.5f * er2[rel[i]];
    e2gs[pos] = make_float2(LRELU(z2), p.y);
}

// ---- fused level-2 softmax + spmm + class-dot, one wave/class ----
// 16 rows in flight per batch (256B each) to deepen the MLP chain.
__global__ __launch_bounds__(256) void k_spmm2(
    const int* __restrict__ off, const int* __restrict__ cnt,
    const float2* __restrict__ e2gs, const unsigned* __restrict__ xrtn_b,
    float* __restrict__ xclass, const float* __restrict__ ac,
    const float* __restrict__ eh4, const int* __restrict__ hclass,
    float* __restrict__ zc, unsigned* __restrict__ m3, int NC) {
    int lane = threadIdx.x & 63;
    int c = blockIdx.x * 4 + (threadIdx.x >> 6);
    if (c >= NC) return;
    int n = cnt[c];
    float a0 = 0.f, a1 = 0.f;
    if (n > 0) {
        int base = off[c];
        float m = -3.4e38f, s = 0.f;
        for (int j = lane; j < n; j += 64) {
            float z = e2gs[base + j].x;
            if (z > m) { s = s * __expf(m - z) + 1.f; m = z; }
            else s += __expf(z - m);
        }
        float M = wredmax(m);
        s = wred(s * __expf(m - M));
        float inv = 1.f / (s + 1e-16f);
        for (int j0 = 0; j0 < n; j0 += 64) {
            int lim = n - j0;
            if (lim > 64) lim = 64;
            float wv = 0.f;
            int g = 0;
            if (lane < lim) {
                float2 pg = e2gs[base + j0 + lane];
                wv = __expf(pg.x - M) * inv;
                g = __float_as_int(pg.y);
            }
            int jj = 0;
            for (; jj + 16 <= lim; jj += 16) {  // 16 rows in flight
                float w16[16];
                int g16[16];
#pragma unroll
                for (int q = 0; q < 16; q++) {
                    w16[q] = __shfl(wv, jj + q);
                    g16[q] = __shfl(g, jj + q);
                }
                unsigned u16[16];
#pragma unroll
                for (int q = 0; q < 16; q++)
                    u16[q] = xrtn_b[(size_t)g16[q] * 64 + lane];
#pragma unroll
                for (int q = 0; q < 16; q++) {
                    a0 = fmaf(w16[q], bu2f((unsigned short)(u16[q] & 0xffff)), a0);
                    a1 = fmaf(w16[q], bu2f((unsigned short)(u16[q] >> 16)), a1);
                }
            }
            for (; jj + 8 <= lim; jj += 8) {   // 8-row remainder batch
                float w8[8];
                int g8[8];
#pragma unroll
                for (int q = 0; q < 8; q++) {
                    w8[q] = __shfl(wv, jj + q);
                    g8[q] = __shfl(g, jj + q);
                }
                unsigned u8[8];
#pragma unroll
                for (int q = 0; q < 8; q++)
                    u8[q] = xrtn_b[(size_t)g8[q] * 64 + lane];
#pragma unroll
                for (int q = 0; q < 8; q++) {
                    a0 = fmaf(w8[q], bu2f((unsigned short)(u8[q] & 0xffff)), a0);
                    a1 = fmaf(w8[q], bu2f((unsigned short)(u8[q] >> 16)), a1);
                }
            }
            for (; jj < lim; jj++) {
                float wj = __shfl(wv, jj);
                unsigned u = xrtn_b[(size_t)__shfl(g, jj) * 64 + lane];
                a0 = fmaf(wj, bu2f((unsigned short)(u & 0xffff)), a0);
                a1 = fmaf(wj, bu2f((unsigned short)(u >> 16)), a1);
            }
        }
    }
    *(float2*)&xclass[(size_t)c * 128 + 2 * lane] = make_float2(a0, a1);
    float p = wred(a0 * ac[2 * lane] + a1 * ac[2 * lane + 1]);
    if (lane == 0) {
        int hc = hclass[c];
        float z = LRELU(p + eh4[hc]);
        zc[c] = z;
        atomicMax(&m3[hc], fenc(z));
    }
}

// ---- level 3: class -> head entity ----
__global__ __launch_bounds__(256) void k_class2(
    const int* __restrict__ hclass, float* __restrict__ zc,
    const unsigned* __restrict__ m3, float* __restrict__ s3,
    float* __restrict__ xeh, int NC) {
    int lane = threadIdx.x & 63;
    int c = blockIdx.x * 4 + (threadIdx.x >> 6);
    if (c >= NC) return;
    int hc = hclass[c];
    *(float2*)&xeh[(size_t)hc * 128 + 2 * lane] = make_float2(0.f, 0.f);
    if (lane == 0) {
        float ex = expf(zc[c] - fdec(m3[hc]));
        zc[c] = ex;
        atomicAdd(&s3[hc], ex);
    }
}

__global__ __launch_bounds__(256) void k_class3(
    const int* __restrict__ hclass, const float* __restrict__ zc,
    const float* __restrict__ s3, const float* __restrict__ xclass,
    float* __restrict__ xeh, int NC) {
    int lane = threadIdx.x & 63;
    int c = blockIdx.x * 4 + (threadIdx.x >> 6);
    if (c >= NC) return;
    int hc = hclass[c];
    float gama = zc[c] / (s3[hc] + 1e-16f);
    float v0 = xclass[(size_t)c * 128 + lane], v1 = xclass[(size_t)c * 128 + 64 + lane];
    atomicAdd(&xeh[(size_t)hc * 128 + lane], gama * v0);
    atomicAdd(&xeh[(size_t)hc * 128 + 64 + lane], gama * v1);
}

extern "C" void kernel_launch(void* const* d_in, const int* in_sizes, int n_in,
                              void* d_out, int out_size, void* d_ws, size_t ws_size,
                              hipStream_t stream) {
    (void)n_in; (void)out_size; (void)ws_size;
    const float* xe   = (const float*)d_in[0];
    const int*   eidx = (const int*)d_in[1];
    const int*   rel  = (const int*)d_in[2];
    const float* remb = (const float*)d_in[4];
    const int*   cidx = (const int*)d_in[5];
    const int*   hcls = (const int*)d_in[6];
    const float* ah2  = (const float*)d_in[8];
    const float* ah3  = (const float*)d_in[9];
    const float* ah4  = (const float*)d_in[10];
    const float* at2  = (const float*)d_in[12];
    const float* at3  = (const float*)d_in[13];
    const float* ar2  = (const float*)d_in[15];
    const float* ac   = (const float*)d_in[16];
    const float* wh   = (const float*)d_in[17];
    const float* wt   = (const float*)d_in[18];
    const float* hww  = (const float*)d_in[19];
    const float* hwb  = (const float*)d_in[20];
    float* out = (float*)d_out;

    const int NE = in_sizes[0] / 256;
    const int E  = in_sizes[2];
    const int NR = in_sizes[4] / 128;
    const int NC = in_sizes[6];
    const int* hidx = eidx;
    const int* tidx = eidx + E;

    char* base = (char*)d_ws;
    size_t off0 = 0;
    auto alloc = [&](size_t bytes) -> char* {
        char* r = base + off0;
        off0 = (off0 + bytes + 255) & ~(size_t)255;
        return r;
    };
    float* hb   = (float*)alloc((size_t)NE * 4);
    float* eh4b = (float*)alloc((size_t)NE * 4);
    float2* pta = (float2*)alloc((size_t)NE * 8);
    float* er2b = (float*)alloc((size_t)NR * 4);
    float2* e2gs = (float2*)alloc((size_t)E * 8);
    float* zc   = (float*)alloc((size_t)NC * 4);
    unsigned short* wtb_hi = (unsigned short*)alloc((size_t)256 * 256 * 2);
    unsigned short* hwt_hi = (unsigned short*)alloc((size_t)128 * 128 * 2);
    unsigned short* xrh_hi = (unsigned short*)alloc((size_t)NE * 128 * 2);
    unsigned short* xrtn   = (unsigned short*)alloc((size_t)NE * 128 * 2);
    int* offb = (int*)alloc((size_t)NC * 4);
    int* curb = (int*)alloc((size_t)NC * 4);
    float* xclass = (float*)alloc((size_t)NC * 128 * 4);
    float* xeh    = (float*)alloc((size_t)NE * 128 * 4);  // zeroed per-launch by
    // k_class2 for touched hc only; untouched rows never read (m3 guard).
    size_t zoff = off0;  // everything below is zero-initialized per launch
    unsigned* m3 = (unsigned*)alloc((size_t)NE * 4);
    float* s3    = (float*)alloc((size_t)NE * 4);
    int* cntb    = (int*)alloc((size_t)NC * 4);
    size_t zbytes = off0 - zoff;

    hipMemsetAsync(base + zoff, 0, zbytes, stream);

    // fused prelude: convW + rel + hist
    int nbConv = (256 * 256 + 128 * 128 + 255) / 256;
    int nbRel  = (NR + 3) / 4;
    int nbHist = (E + 255) / 256;
    k_prelude<<<nbConv + nbRel + nbHist, 256, 0, stream>>>(
        wh, wt, hww, wtb_hi, hwt_hi, remb, ar2, er2b, NR, cidx, cntb, E,
        nbConv, nbRel);

    // projection GEMM: 8-wave block, A reg-staged bf16 (48KB LDS)
    k_mm_proj<<<(NE + 127) / 128, 512, 0, stream>>>(
        xe, wtb_hi, xrh_hi, xrtn, NE,
        ah2, ah3, ah4, at2, at3, hb, eh4b, pta, tidx);

    k_scan<<<1, 1024, 0, stream>>>(cntb, offb, curb, NC);

    // fused level-2 logit + scatter (level-1 softmax cancels vs F.normalize)
    k_edgescatter<<<(E + 255) / 256, 256, 0, stream>>>(
        cidx, curb, hidx, tidx, rel, pta, hb, er2b, e2gs, E);

    k_spmm2<<<(NC + 3) / 4, 256, 0, stream>>>(offb, cntb, e2gs,
                                              (const unsigned*)xrtn, xclass,
                                              ac, eh4b, hcls, zc, m3, NC);
    k_class2<<<(NC + 3) / 4, 256, 0, stream>>>(hcls, zc, m3, s3, xeh, NC);
    k_class3<<<(NC + 3) / 4, 256, 0, stream>>>(hcls, zc, s3, xclass, xeh, NC);

    k_mm_hw<<<(NE + 255) / 256, 512, 0, stream>>>(
        xrh_hi, hwt_hi, out, hwb, xeh, m3, NE);
}

// Round 23
// 258.479 us; speedup vs baseline: 1.0247x; 1.0247x over previous
//
#include <hip/hip_runtime.h>
#include <hip/hip_bf16.h>

#define LRELU(x) ((x) >= 0.f ? (x) : 0.01f * (x))

typedef __attribute__((ext_vector_type(8))) short short8v;
typedef __attribute__((ext_vector_type(4))) float f32x4;

__device__ inline unsigned fenc(float x) {
    unsigned u = __float_as_uint(x);
    return (u & 0x80000000u) ? ~u : (u | 0x80000000u);
}
__device__ inline float fdec(unsigned e) {
    return __uint_as_float((e & 0x80000000u) ? (e ^ 0x80000000u) : ~e);
}

__device__ inline float wred(float v) {
#pragma unroll
    for (int o = 32; o > 0; o >>= 1) v += __shfl_xor(v, o, 64);
    return v;
}
__device__ inline float wredmax(float v) {
#pragma unroll
    for (int o = 32; o > 0; o >>= 1) v = fmaxf(v, __shfl_xor(v, o, 64));
    return v;
}

__device__ inline unsigned short f2bu(float x) {
    __hip_bfloat16 b = __float2bfloat16(x);
    return *reinterpret_cast<unsigned short*>(&b);
}
__device__ inline float bu2f(unsigned short u) {
    return __uint_as_float((unsigned)u << 16);
}

__device__ inline f32x4 mfma16(short8v a, short8v b, f32x4 c) {
    return __builtin_amdgcn_mfma_f32_16x16x32_bf16(a, b, c, 0, 0, 0);
}

// async global->LDS, 16B per lane, dest = (wave-uniform base) + lane*16
__device__ inline void gload16(const void* g, void* l) {
    __builtin_amdgcn_global_load_lds(
        (const __attribute__((address_space(1))) void*)g,
        (__attribute__((address_space(3))) void*)l, 16, 0, 0);
}

// ---- fused prelude: convW + rel-dot + class histogram in ONE launch ----
__global__ __launch_bounds__(256) void k_prelude(
    const float* __restrict__ wh, const float* __restrict__ wt,
    const float* __restrict__ hww, unsigned short* __restrict__ wtb_hi,
    unsigned short* __restrict__ hwt_hi,
    const float* __restrict__ remb, const float* __restrict__ ar2,
    float* __restrict__ er2, int NR,
    const int* __restrict__ cidx, int* __restrict__ cnt, int E,
    int nbConv, int nbRel) {
    int bx = blockIdx.x, tid = threadIdx.x;
    if (bx < nbConv) {
        int id = bx * 256 + tid;
        if (id < 256 * 256) {
            int n = id >> 8, k = id & 255;
            float v = (n < 128) ? wh[(size_t)k * 128 + n]
                                : wt[(size_t)k * 128 + (n - 128)];
            wtb_hi[(size_t)n * 256 + k] = f2bu(v);
        } else {
            int id2 = id - 256 * 256;
            if (id2 < 128 * 128) {
                int n = id2 >> 7, k = id2 & 127;
                hwt_hi[(size_t)n * 128 + k] = f2bu(hww[(size_t)k * 128 + n]);
            }
        }
    } else if (bx < nbConv + nbRel) {
        int lane = tid & 63;
        int r = (bx - nbConv) * 4 + (tid >> 6);
        if (r >= NR) return;
        float v0 = remb[(size_t)r * 128 + lane];
        float v1 = remb[(size_t)r * 128 + 64 + lane];
        float p2 = wred(v0 * ar2[lane] + v1 * ar2[64 + lane]);
        if (lane == 0) er2[r] = p2;
    } else {
        int i = (bx - nbConv - nbRel) * 256 + tid;
        if (i >= E) return;
        atomicAdd(&cnt[cidx[i]], 1);
    }
}

// ---- projection GEMM: 8-wave block, both col-halves, A reg-staged bf16 ----
__global__ __launch_bounds__(512) void k_mm_proj(
    const float* __restrict__ Af32, const unsigned short* __restrict__ Bh,
    unsigned short* __restrict__ oh0, unsigned short* __restrict__ oh1, int M,
    const float* __restrict__ ah2, const float* __restrict__ ah3,
    const float* __restrict__ ah4, const float* __restrict__ at2,
    const float* __restrict__ at3,
    float* __restrict__ hb, float* __restrict__ eh4o,
    float2* __restrict__ pta, const int* __restrict__ tidxg) {
    constexpr int KD = 256;
    constexpr int NSTEP = KD / 32;
    __shared__ unsigned short As_h[2][128 * 32];
    __shared__ unsigned short Bs_h[2][256 * 32];

    int row0 = blockIdx.x * 128;
    if (row0 + 128 > M) row0 = M - 128;
    int tid = threadIdx.x, w = tid >> 6, l = tid & 63;
    int rg = w & 3, ch = w >> 2;
    int lr = l & 15, hi4 = l >> 4;
    int srow = l >> 2, sslot = l & 3;
    int arow = tid >> 2, asg = tid & 3;
    int asgl = asg ^ ((arow >> 1) & 3);
    float4 rA0, rA1;

    f32x4 acc[2][8];
#pragma unroll
    for (int i = 0; i < 2; i++)
#pragma unroll
        for (int j = 0; j < 8; j++) acc[i][j] = (f32x4){0.f, 0.f, 0.f, 0.f};

    auto loadA = [&](int s) {
        const float* p = Af32 + (size_t)(row0 + arow) * KD + s * 32 + asgl * 8;
        rA0 = *(const float4*)p;
        rA1 = *(const float4*)(p + 4);
    };
    auto writeA = [&](int b) {
        short8v v;
        v[0] = (short)f2bu(rA0.x); v[1] = (short)f2bu(rA0.y);
        v[2] = (short)f2bu(rA0.z); v[3] = (short)f2bu(rA0.w);
        v[4] = (short)f2bu(rA1.x); v[5] = (short)f2bu(rA1.y);
        v[6] = (short)f2bu(rA1.z); v[7] = (short)f2bu(rA1.w);
        *(short8v*)&As_h[b][arow * 32 + asg * 8] = v;
    };
    auto stageB = [&](int s, int b) {
        int k0 = s * 32;
#pragma unroll
        for (int i = 0; i < 2; i++) {
            int ub = w * 2 + i;
            int n = ub * 16 + srow;
            int klog = (sslot ^ ((n >> 1) & 3)) * 8;
            gload16(Bh + (size_t)n * KD + k0 + klog,
                    (char*)&Bs_h[b][0] + ub * 1024);
        }
    };

    loadA(0);
    stageB(0, 0);
    writeA(0);
    __syncthreads();
    for (int s = 0; s < NSTEP; s++) {
        int b = s & 1;
        if (s + 1 < NSTEP) {
            loadA(s + 1);
            stageB(s + 1, b ^ 1);
        }

        short8v am_h[2];
#pragma unroll
        for (int mr = 0; mr < 2; mr++) {
            int r = rg * 32 + mr * 16 + lr;
            int ko = (hi4 ^ ((r >> 1) & 3)) * 8;
            am_h[mr] = *(const short8v*)&As_h[b][r * 32 + ko];
        }
#pragma unroll
        for (int ncc = 0; ncc < 8; ncc += 4) {
            short8v bn_h[4];
#pragma unroll
            for (int j = 0; j < 4; j++) {
                int n = ch * 128 + (ncc + j) * 16 + lr;
                int ko = (hi4 ^ ((n >> 1) & 3)) * 8;
                bn_h[j] = *(const short8v*)&Bs_h[b][n * 32 + ko];
            }
#pragma unroll
            for (int mr = 0; mr < 2; mr++)
#pragma unroll
                for (int j = 0; j < 4; j++)
                    acc[mr][ncc + j] = mfma16(am_h[mr], bn_h[j], acc[mr][ncc + j]);
        }
        if (s + 1 < NSTEP) writeA(b ^ 1);
        __syncthreads();
    }

    unsigned short* OH = ch ? oh1 : oh0;
    const float* v1 = ch ? at2 : ah2;
    const float* v2 = ch ? at3 : ah3;
#pragma unroll
    for (int mr = 0; mr < 2; mr++)
#pragma unroll
        for (int rr = 0; rr < 4; rr++) {
            int row = row0 + rg * 32 + mr * 16 + hi4 * 4 + rr;
            float d0 = 0.f, d1 = 0.f, d2 = 0.f;
#pragma unroll
            for (int nc = 0; nc < 8; nc++) {
                float v = fmaxf(acc[mr][nc][rr], 0.f);
                int col = nc * 16 + lr;
                d0 = fmaf(v, v1[col], d0);
                d1 = fmaf(v, v2[col], d1);
                d2 = ch ? fmaf(v, v, d2) : fmaf(v, ah4[col], d2);
            }
#pragma unroll
            for (int o = 1; o <= 8; o <<= 1) {
                d0 += __shfl_xor(d0, o, 64);
                d1 += __shfl_xor(d1, o, 64);
                d2 += __shfl_xor(d2, o, 64);
            }
            float inv = 1.f;
            if (ch) inv = 1.f / fmaxf(sqrtf(d2), 1e-12f);
#pragma unroll
            for (int nc = 0; nc < 8; nc++) {
                float v = fmaxf(acc[mr][nc][rr], 0.f);
                OH[(size_t)row * 128 + nc * 16 + lr] = f2bu(ch ? v * inv : v);
            }
            if (lr == 0) {
                if (ch == 0) {
                    hb[row] = d0 + 0.25f * d1;
                    eh4o[row] = d2;
                } else {
                    float tav = (d0 + 0.25f * d1) * inv;
                    pta[row] = make_float2(tav, __int_as_float(tidxg[row]));
                }
            }
        }
}

// ---- highway GEMM: 8-wave 256-row block (KD=128, A bf16) ----
__global__ __launch_bounds__(512) void k_mm_hw(
    const unsigned short* __restrict__ Ah, const unsigned short* __restrict__ Bh,
    float* __restrict__ o0, const float* __restrict__ bias,
    const float* __restrict__ xeh, const unsigned* __restrict__ m3f, int M) {
    constexpr int KD = 128;
    constexpr int NSTEP = KD / 32;
    __shared__ unsigned short As_h[2][256 * 32];
    __shared__ unsigned short Bs_h[2][128 * 32];

    int row0 = blockIdx.x * 256;
    if (row0 + 256 > M) row0 = M - 256;
    int tid = threadIdx.x, w = tid >> 6, l = tid & 63;
    int lr = l & 15, hi4 = l >> 4;
    int srow = l >> 2, sslot = l & 3;

    f32x4 acc[2][8];
#pragma unroll
    for (int i = 0; i < 2; i++)
#pragma unroll
        for (int j = 0; j < 8; j++) acc[i][j] = (f32x4){0.f, 0.f, 0.f, 0.f};

    auto stage = [&](int s, int b) {
        int k0 = s * 32;
#pragma unroll
        for (int i = 0; i < 3; i++) {
            int u = w * 3 + i;
            if (u < 16) {
                int row = u * 16 + srow;
                int klog = (sslot ^ ((row >> 1) & 3)) * 8;
                gload16(Ah + (size_t)(row0 + row) * KD + k0 + klog,
                        (char*)&As_h[b][0] + u * 1024);
            } else {
                int ub = u - 16;
                int row = ub * 16 + srow;
                int klog = (sslot ^ ((row >> 1) & 3)) * 8;
                gload16(Bh + (size_t)row * KD + k0 + klog,
                        (char*)&Bs_h[b][0] + ub * 1024);
            }
        }
    };

    stage(0, 0);
    __syncthreads();
    for (int s = 0; s < NSTEP; s++) {
        int b = s & 1;
        if (s + 1 < NSTEP) stage(s + 1, b ^ 1);
        short8v am_h[2];
#pragma unroll
        for (int mr = 0; mr < 2; mr++) {
            int r = w * 32 + mr * 16 + lr;
            int ko = (hi4 ^ ((r >> 1) & 3)) * 8;
            am_h[mr] = *(const short8v*)&As_h[b][r * 32 + ko];
        }
#pragma unroll
        for (int ncc = 0; ncc < 8; ncc += 4) {
            short8v bn_h[4];
#pragma unroll
            for (int j = 0; j < 4; j++) {
                int n = (ncc + j) * 16 + lr;
                int ko = (hi4 ^ ((n >> 1) & 3)) * 8;
                bn_h[j] = *(const short8v*)&Bs_h[b][n * 32 + ko];
            }
#pragma unroll
            for (int mr = 0; mr < 2; mr++)
#pragma unroll
                for (int j = 0; j < 4; j++)
                    acc[mr][ncc + j] = mfma16(am_h[mr], bn_h[j], acc[mr][ncc + j]);
        }
        __syncthreads();
    }

#pragma unroll
    for (int mr = 0; mr < 2; mr++)
#pragma unroll
        for (int rr = 0; rr < 4; rr++) {
            int row = row0 + w * 32 + mr * 16 + hi4 * 4 + rr;
            bool touched = (m3f[row] != 0u);
#pragma unroll
            for (int nc = 0; nc < 8; nc++) {
                int col = nc * 16 + lr;
                float a = acc[mr][nc][rr] + bias[col];
                float g = 1.f / (1.f + expf(-a));
                size_t o = (size_t)row * 128 + col;
                float af = bu2f(Ah[o]);
                float xv = 0.f;
                if (touched) xv = xeh[o];
                o0[o] = g * xv + (1.f - g) * af;
            }
        }
}

__global__ __launch_bounds__(1024) void k_scan(const int* __restrict__ cnt,
                                               int* __restrict__ off,
                                               int* __restrict__ cur, int NC) {
    __shared__ int wt[16];
    __shared__ int sbase;
    int tid = threadIdx.x, w = tid >> 6, lane = tid & 63;
    if (tid == 0) sbase = 0;
    __syncthreads();
    for (int c0 = 0; c0 < NC; c0 += 1024) {
        int c = c0 + tid;
        int v = (c < NC) ? cnt[c] : 0;
        int x = v;
#pragma unroll
        for (int o = 1; o < 64; o <<= 1) {
            int t = __shfl_up(x, o, 64);
            if (lane >= o) x += t;
        }
        if (lane == 63) wt[w] = x;
        __syncthreads();
        int pre = 0, tot = 0;
#pragma unroll
        for (int i = 0; i < 16; i++) {
            int t = wt[i];
            tot += t;
            if (i < w) pre += t;
        }
        int excl = sbase + pre + x - v;
        if (c < NC) { off[c] = excl; cur[c] = excl; }
        __syncthreads();
        if (tid == 0) sbase += tot;
        __syncthreads();
    }
}

// ---- fused level-2 logit + scatter (packed 8B gather + packed 8B write) ----
__global__ __launch_bounds__(256) void k_edgescatter(
    const int* __restrict__ cidx, int* __restrict__ cur,
    const int* __restrict__ hidx, const int* __restrict__ tidx,
    const int* __restrict__ rel, const float2* __restrict__ pta,
    const float* __restrict__ hb, const float* __restrict__ er2,
    float2* __restrict__ e2gs, int E) {
    int i = blockIdx.x * 256 + threadIdx.x;
    if (i >= E) return;
    int pos = atomicAdd(&cur[cidx[i]], 1);
    float2 p = pta[tidx[i]];
    float z2 = p.x + hb[hidx[i]] + 0.5f * er2[rel[i]];
    e2gs[pos] = make_float2(LRELU(z2), p.y);
}

// ---- fused level-2 softmax + spmm + class-dot: SINGLE PASS (online max) ----
// Per 64-edge batch: batch max -> rescale running acc by exp(M_old-M_new),
// accumulate unnormalized exp(z-M)-weighted rows + per-lane denominators;
// divide once at the end. e2gs read ONCE.
__global__ __launch_bounds__(256) void k_spmm2(
    const int* __restrict__ off, const int* __restrict__ cnt,
    const float2* __restrict__ e2gs, const unsigned* __restrict__ xrtn_b,
    float* __restrict__ xclass, const float* __restrict__ ac,
    const float* __restrict__ eh4, const int* __restrict__ hclass,
    float* __restrict__ zc, unsigned* __restrict__ m3, int NC) {
    int lane = threadIdx.x & 63;
    int c = blockIdx.x * 4 + (threadIdx.x >> 6);
    if (c >= NC) return;
    int n = cnt[c];
    float a0 = 0.f, a1 = 0.f;
    if (n > 0) {
        int base = off[c];
        float M = -3.4e38f, sl = 0.f;
        for (int j0 = 0; j0 < n; j0 += 64) {
            int lim = n - j0;
            if (lim > 64) lim = 64;
            float z = -3.4e38f;
            int g = 0;
            if (lane < lim) {
                float2 pg = e2gs[base + j0 + lane];
                z = pg.x;
                g = __float_as_int(pg.y);
            }
            float bm = wredmax(z);
            if (bm > M) {                      // rescale running state
                float sc = __expf(M - bm);
                a0 *= sc; a1 *= sc; sl *= sc;
                M = bm;
            }
            float wv = (lane < lim) ? __expf(z - M) : 0.f;
            sl += wv;
            int jj = 0;
            for (; jj + 8 <= lim; jj += 8) {   // 8 rows in flight, 256B each
                float w8[8];
                int g8[8];
#pragma unroll
                for (int q = 0; q < 8; q++) {
                    w8[q] = __shfl(wv, jj + q);
                    g8[q] = __shfl(g, jj + q);
                }
                unsigned u8[8];
#pragma unroll
                for (int q = 0; q < 8; q++)
                    u8[q] = xrtn_b[(size_t)g8[q] * 64 + lane];
#pragma unroll
                for (int q = 0; q < 8; q++) {
                    a0 = fmaf(w8[q], bu2f((unsigned short)(u8[q] & 0xffff)), a0);
                    a1 = fmaf(w8[q], bu2f((unsigned short)(u8[q] >> 16)), a1);
                }
            }
            for (; jj < lim; jj++) {
                float wj = __shfl(wv, jj);
                unsigned u = xrtn_b[(size_t)__shfl(g, jj) * 64 + lane];
                a0 = fmaf(wj, bu2f((unsigned short)(u & 0xffff)), a0);
                a1 = fmaf(wj, bu2f((unsigned short)(u >> 16)), a1);
            }
        }
        float S = wred(sl);
        float invS = 1.f / (S + 1e-16f);
        a0 *= invS;
        a1 *= invS;
    }
    *(float2*)&xclass[(size_t)c * 128 + 2 * lane] = make_float2(a0, a1);
    // fused class-level dot: e_c = xclass[c]·ac + eh4[hclass[c]]
    float p = wred(a0 * ac[2 * lane] + a1 * ac[2 * lane + 1]);
    if (lane == 0) {
        int hc = hclass[c];
        float z = LRELU(p + eh4[hc]);
        zc[c] = z;
        atomicMax(&m3[hc], fenc(z));
    }
}

// ---- level 3: class -> head entity ----
__global__ __launch_bounds__(256) void k_class2(
    const int* __restrict__ hclass, float* __restrict__ zc,
    const unsigned* __restrict__ m3, float* __restrict__ s3,
    float* __restrict__ xeh, int NC) {
    int lane = threadIdx.x & 63;
    int c = blockIdx.x * 4 + (threadIdx.x >> 6);
    if (c >= NC) return;
    int hc = hclass[c];
    *(float2*)&xeh[(size_t)hc * 128 + 2 * lane] = make_float2(0.f, 0.f);
    if (lane == 0) {
        float ex = expf(zc[c] - fdec(m3[hc]));
        zc[c] = ex;
        atomicAdd(&s3[hc], ex);
    }
}

__global__ __launch_bounds__(256) void k_class3(
    const int* __restrict__ hclass, const float* __restrict__ zc,
    const float* __restrict__ s3, const float* __restrict__ xclass,
    float* __restrict__ xeh, int NC) {
    int lane = threadIdx.x & 63;
    int c = blockIdx.x * 4 + (threadIdx.x >> 6);
    if (c >= NC) return;
    int hc = hclass[c];
    float gama = zc[c] / (s3[hc] + 1e-16f);
    float v0 = xclass[(size_t)c * 128 + lane], v1 = xclass[(size_t)c * 128 + 64 + lane];
    atomicAdd(&xeh[(size_t)hc * 128 + lane], gama * v0);
    atomicAdd(&xeh[(size_t)hc * 128 + 64 + lane], gama * v1);
}

extern "C" void kernel_launch(void* const* d_in, const int* in_sizes, int n_in,
                              void* d_out, int out_size, void* d_ws, size_t ws_size,
                              hipStream_t stream) {
    (void)n_in; (void)out_size; (void)ws_size;
    const float* xe   = (const float*)d_in[0];
    const int*   eidx = (const int*)d_in[1];
    const int*   rel  = (const int*)d_in[2];
    const float* remb = (const float*)d_in[4];
    const int*   cidx = (const int*)d_in[5];
    const int*   hcls = (const int*)d_in[6];
    const float* ah2  = (const float*)d_in[8];
    const float* ah3  = (const float*)d_in[9];
    const float* ah4  = (const float*)d_in[10];
    const float* at2  = (const float*)d_in[12];
    const float* at3  = (const float*)d_in[13];
    const float* ar2  = (const float*)d_in[15];
    const float* ac   = (const float*)d_in[16];
    const float* wh   = (const float*)d_in[17];
    const float* wt   = (const float*)d_in[18];
    const float* hww  = (const float*)d_in[19];
    const float* hwb  = (const float*)d_in[20];
    float* out = (float*)d_out;

    const int NE = in_sizes[0] / 256;
    const int E  = in_sizes[2];
    const int NR = in_sizes[4] / 128;
    const int NC = in_sizes[6];
    const int* hidx = eidx;
    const int* tidx = eidx + E;

    char* base = (char*)d_ws;
    size_t off0 = 0;
    auto alloc = [&](size_t bytes) -> char* {
        char* r = base + off0;
        off0 = (off0 + bytes + 255) & ~(size_t)255;
        return r;
    };
    float* hb   = (float*)alloc((size_t)NE * 4);
    float* eh4b = (float*)alloc((size_t)NE * 4);
    float2* pta = (float2*)alloc((size_t)NE * 8);
    float* er2b = (float*)alloc((size_t)NR * 4);
    float2* e2gs = (float2*)alloc((size_t)E * 8);
    float* zc   = (float*)alloc((size_t)NC * 4);
    unsigned short* wtb_hi = (unsigned short*)alloc((size_t)256 * 256 * 2);
    unsigned short* hwt_hi = (unsigned short*)alloc((size_t)128 * 128 * 2);
    unsigned short* xrh_hi = (unsigned short*)alloc((size_t)NE * 128 * 2);
    unsigned short* xrtn   = (unsigned short*)alloc((size_t)NE * 128 * 2);
    int* offb = (int*)alloc((size_t)NC * 4);
    int* curb = (int*)alloc((size_t)NC * 4);
    float* xclass = (float*)alloc((size_t)NC * 128 * 4);
    float* xeh    = (float*)alloc((size_t)NE * 128 * 4);  // zeroed per-launch by
    // k_class2 for touched hc only; untouched rows never read (m3 guard).
    size_t zoff = off0;  // everything below is zero-initialized per launch
    unsigned* m3 = (unsigned*)alloc((size_t)NE * 4);
    float* s3    = (float*)alloc((size_t)NE * 4);
    int* cntb    = (int*)alloc((size_t)NC * 4);
    size_t zbytes = off0 - zoff;

    hipMemsetAsync(base + zoff, 0, zbytes, stream);

    // fused prelude: convW + rel + hist
    int nbConv = (256 * 256 + 128 * 128 + 255) / 256;
    int nbRel  = (NR + 3) / 4;
    int nbHist = (E + 255) / 256;
    k_prelude<<<nbConv + nbRel + nbHist, 256, 0, stream>>>(
        wh, wt, hww, wtb_hi, hwt_hi, remb, ar2, er2b, NR, cidx, cntb, E,
        nbConv, nbRel);

    // projection GEMM: 8-wave block, A reg-staged bf16 (48KB LDS)
    k_mm_proj<<<(NE + 127) / 128, 512, 0, stream>>>(
        xe, wtb_hi, xrh_hi, xrtn, NE,
        ah2, ah3, ah4, at2, at3, hb, eh4b, pta, tidx);

    k_scan<<<1, 1024, 0, stream>>>(cntb, offb, curb, NC);

    // fused level-2 logit + scatter (level-1 softmax cancels vs F.normalize)
    k_edgescatter<<<(E + 255) / 256, 256, 0, stream>>>(
        cidx, curb, hidx, tidx, rel, pta, hb, er2b, e2gs, E);

    k_spmm2<<<(NC + 3) / 4, 256, 0, stream>>>(offb, cntb, e2gs,
                                              (const unsigned*)xrtn, xclass,
                                              ac, eh4b, hcls, zc, m3, NC);
    k_class2<<<(NC + 3) / 4, 256, 0, stream>>>(hcls, zc, m3, s3, xeh, NC);
    k_class3<<<(NC + 3) / 4, 256, 0, stream>>>(hcls, zc, s3, xclass, xeh, NC);

    k_mm_hw<<<(NE + 255) / 256, 512, 0, stream>>>(
        xrh_hi, hwt_hi, out, hwb, xeh, m3, NE);
}